// Round 2
// baseline (3450.158 us; speedup 1.0000x reference)
//
#include <hip/hip_runtime.h>
#include <math.h>

// MambaBlock: B=8, T=2048, D_MODEL=1024, D_STATE=256, all fp32.
//
// ws layout (176 MB):
//   u   = x @ W_in + b_in                       [16384,256]   ws +   0 MB
//   u2  = u @ Bm                                [16384,256]   ws +  16 MB
//   h   = scan(tanh(h@A + u2_t))                [16384,256]   ws +  32 MB
//   big = u @ D^T  (+= h @ C^T later)           [16384,1024]  ws +  48 MB
//   g   = sigmoid(x @ W_gate + b_gate)          [16384,1024]  ws + 112 MB
//   out = (g*big+(1-g)*x) @ W_out + b_out + x   d_out

enum { E_NONE = 0, E_BIAS = 1, E_SIG = 2, E_ACC = 3, E_BIASRES = 4 };

// ---------------- fp32 tile GEMM (unchanged from R1) ----------------
template <int EPI, bool BT>
__global__ __launch_bounds__(256) void gemm64(
    const float* __restrict__ Ag, const float* __restrict__ Bg,
    const float* __restrict__ bias, const float* __restrict__ res,
    float* Cg, int M, int N, int K)
{
    __shared__ float As[16][68];
    __shared__ float Bs[16][68];
    const int tid = threadIdx.x;
    const int m0 = blockIdx.y * 64, n0 = blockIdx.x * 64;
    const int tm = (tid >> 4) << 2;
    const int tn = (tid & 15) << 2;
    const int arow = tid >> 2;
    const int acol = (tid & 3) << 2;
    const int brow = tid >> 4;
    const int bcol = (tid & 15) << 2;
    float acc[4][4] = {};

    for (int k0 = 0; k0 < K; k0 += 16) {
        float4 a4 = *(const float4*)(Ag + (size_t)(m0 + arow) * K + k0 + acol);
        As[acol + 0][arow] = a4.x; As[acol + 1][arow] = a4.y;
        As[acol + 2][arow] = a4.z; As[acol + 3][arow] = a4.w;
        if (!BT) {
            float4 b4 = *(const float4*)(Bg + (size_t)(k0 + brow) * N + n0 + bcol);
            Bs[brow][bcol + 0] = b4.x; Bs[brow][bcol + 1] = b4.y;
            Bs[brow][bcol + 2] = b4.z; Bs[brow][bcol + 3] = b4.w;
        } else {
            float4 b4 = *(const float4*)(Bg + (size_t)(n0 + arow) * K + k0 + acol);
            Bs[acol + 0][arow] = b4.x; Bs[acol + 1][arow] = b4.y;
            Bs[acol + 2][arow] = b4.z; Bs[acol + 3][arow] = b4.w;
        }
        __syncthreads();
#pragma unroll
        for (int k = 0; k < 16; ++k) {
            float am[4], bv[4];
#pragma unroll
            for (int i = 0; i < 4; ++i) am[i] = As[k][tm + i];
#pragma unroll
            for (int j = 0; j < 4; ++j) bv[j] = Bs[k][tn + j];
#pragma unroll
            for (int i = 0; i < 4; ++i)
#pragma unroll
                for (int j = 0; j < 4; ++j)
                    acc[i][j] = fmaf(am[i], bv[j], acc[i][j]);
        }
        __syncthreads();
    }

#pragma unroll
    for (int i = 0; i < 4; ++i) {
        const int m = m0 + tm + i, n = n0 + tn;
        const size_t idx = (size_t)m * N + n;
        float4 v = make_float4(acc[i][0], acc[i][1], acc[i][2], acc[i][3]);
        if (EPI == E_BIAS || EPI == E_SIG || EPI == E_BIASRES) {
            v.x += bias[n + 0]; v.y += bias[n + 1];
            v.z += bias[n + 2]; v.w += bias[n + 3];
        }
        if (EPI == E_SIG) {
            v.x = 1.f / (1.f + expf(-v.x)); v.y = 1.f / (1.f + expf(-v.y));
            v.z = 1.f / (1.f + expf(-v.z)); v.w = 1.f / (1.f + expf(-v.w));
        }
        if (EPI == E_ACC) {
            float4 c = *(const float4*)(Cg + idx);
            v.x += c.x; v.y += c.y; v.z += c.z; v.w += c.w;
        }
        if (EPI == E_BIASRES) {
            float4 r = *(const float4*)(res + idx);
            v.x += r.x; v.y += r.y; v.z += r.z; v.w += r.w;
        }
        *(float4*)(Cg + idx) = v;
    }
}

// ---------------- MFMA scan ----------------
// One block, 4 waves, all 8 batches. Per step: Y^T = A^T @ H^T via
// mfma_f32_16x16x32_bf16 (M=state 256, N=batch 8 pad 16, K=state 256).
// A^T fragments preloaded to registers (128 VGPR/lane). H kept in LDS as
// bf16, layout [32 kgroups][16 rows][8 bf16], row stride 288B (reads: bank
// = (8g+4r)%32, worst 2-way = free). Double-buffered; 1 barrier/step.
typedef __attribute__((ext_vector_type(8))) short bf16x8;
typedef __attribute__((ext_vector_type(4))) float f32x4;

static __device__ inline unsigned short f2bf(float f) {
    unsigned u = __builtin_bit_cast(unsigned, f);
    unsigned r = (u + 0x7fff + ((u >> 16) & 1)) >> 16;
    return (unsigned short)r;
}
static __device__ inline unsigned pack2(float a, float b) {
    return (unsigned)f2bf(a) | ((unsigned)f2bf(b) << 16);
}
static __device__ inline float tanh_fast(float x) {
    // tanh(x) = 1 - 2/(exp2(x*2/ln2)+1); exact at +-inf, ~1e-6 abs err.
    float e = __builtin_amdgcn_exp2f(x * 2.8853900817779268f);
    float t = __builtin_amdgcn_rcpf(e + 1.0f);
    return fmaf(-2.0f, t, 1.0f);
}

__global__ __launch_bounds__(256, 1) void scan_mfma(
    const float* __restrict__ Amat, const float* __restrict__ u2,
    float* __restrict__ hout)
{
    constexpr int T = 2048;
    constexpr int KGSTRIDE = 288;                 // 16 rows * 16B + 32B pad
    __shared__ unsigned char Hlds[2][32 * KGSTRIDE];

    const int tid = threadIdx.x;
    const int w = tid >> 6;        // wave 0..3, owns states [w*64, w*64+64)
    const int l = tid & 63;
    const int r = l & 15;          // A-frag m / B-frag n / C col (batch)
    const int g = l >> 4;          // k-subgroup / C row-group
    const bool act = (r < 8);      // batches 0..7 real, 8..15 padding

    // zero both H buffers (h0 = 0; pad rows stay 0 forever)
    for (int i = tid; i < 2 * 32 * KGSTRIDE / 4; i += 256)
        ((unsigned*)Hlds)[i] = 0u;

    // Preload A^T fragments: af[mti][kt], lane holds A^T[m][k] = Amat[k][m]
    // with m = w*64+mti*16+r, k = kt*32+g*8+j (j=0..7).
    bf16x8 af[4][8];
#pragma unroll
    for (int mti = 0; mti < 4; ++mti) {
        const int m = w * 64 + mti * 16 + r;
#pragma unroll
        for (int kt = 0; kt < 8; ++kt) {
            unsigned wds[4];
#pragma unroll
            for (int jw = 0; jw < 4; ++jw) {
                const int k = kt * 32 + g * 8 + jw * 2;
                float v0 = Amat[(size_t)k * 256 + m];
                float v1 = Amat[(size_t)(k + 1) * 256 + m];
                wds[jw] = pack2(v0, v1);
            }
            af[mti][kt] = __builtin_bit_cast(bf16x8, *(uint4*)wds);
        }
    }

    // per-lane global base: batch n = r, state col base m = w*64+mti*16+g*4
    const float* u2p[4];
    float* hp[4];
#pragma unroll
    for (int mti = 0; mti < 4; ++mti) {
        const size_t base = ((size_t)r * T) * 256 + (w * 64 + mti * 16 + g * 4);
        u2p[mti] = u2 + base;
        hp[mti]  = hout + base;
    }

    f32x4 cur[4], nxt[4];
    if (act) {
#pragma unroll
        for (int mti = 0; mti < 4; ++mti)
            cur[mti] = *(const f32x4*)(u2p[mti]);   // t = 0
    }
    __syncthreads();

    for (int t = 0; t < T; ++t) {
        const int buf = t & 1;
        // H fragments: lane reads H[batch=r][k = kt*32+g*8 .. +8] (16B)
        bf16x8 hf[8];
#pragma unroll
        for (int kt = 0; kt < 8; ++kt)
            hf[kt] = *(const bf16x8*)(&Hlds[buf][(kt * 4 + g) * KGSTRIDE + r * 16]);

        // prefetch u2 for t+1
        if (act && t + 1 < T) {
#pragma unroll
            for (int mti = 0; mti < 4; ++mti)
                nxt[mti] = *(const f32x4*)(u2p[mti] + (size_t)(t + 1) * 256);
        }

#pragma unroll
        for (int mti = 0; mti < 4; ++mti) {
            f32x4 acc = {0.f, 0.f, 0.f, 0.f};
#pragma unroll
            for (int kt = 0; kt < 8; ++kt)
                acc = __builtin_amdgcn_mfma_f32_16x16x32_bf16(
                    af[mti][kt], hf[kt], acc, 0, 0, 0);
            if (act) {
                f32x4 hv;
#pragma unroll
                for (int q = 0; q < 4; ++q)
                    hv[q] = tanh_fast(acc[q] + cur[mti][q]);
                *(f32x4*)(hp[mti] + (size_t)t * 256) = hv;  // fp32 h to global
                // bf16 h into the other LDS buffer for the next step
                const int m = w * 64 + mti * 16 + g * 4;
                const int kg = m >> 3;
                const int off = kg * KGSTRIDE + r * 16 + (m & 7) * 2;
                uint2 pk = make_uint2(pack2(hv[0], hv[1]), pack2(hv[2], hv[3]));
                *(uint2*)(&Hlds[buf ^ 1][off]) = pk;
            }
        }
        __syncthreads();
        if (act) {
#pragma unroll
            for (int mti = 0; mti < 4; ++mti) cur[mti] = nxt[mti];
        }
    }
}

// ---------------- elementwise gate ----------------
__global__ void ewise(const float* g, const float* __restrict__ big,
                      const float* __restrict__ x, float* ys, int n4)
{
    int i = blockIdx.x * blockDim.x + threadIdx.x;
    if (i >= n4) return;
    float4 gv = ((const float4*)g)[i];
    float4 bv = ((const float4*)big)[i];
    float4 xv = ((const float4*)x)[i];
    float4 r;
    r.x = gv.x * bv.x + (1.f - gv.x) * xv.x;
    r.y = gv.y * bv.y + (1.f - gv.y) * xv.y;
    r.z = gv.z * bv.z + (1.f - gv.z) * xv.z;
    r.w = gv.w * bv.w + (1.f - gv.w) * xv.w;
    ((float4*)ys)[i] = r;
}

extern "C" void kernel_launch(void* const* d_in, const int* in_sizes, int n_in,
                              void* d_out, int out_size, void* d_ws, size_t ws_size,
                              hipStream_t stream)
{
    const float* x      = (const float*)d_in[0];
    const float* W_in   = (const float*)d_in[1];
    const float* b_in   = (const float*)d_in[2];
    const float* W_gate = (const float*)d_in[3];
    const float* b_gate = (const float*)d_in[4];
    const float* Amat   = (const float*)d_in[5];
    const float* Bm     = (const float*)d_in[6];
    const float* Cm     = (const float*)d_in[7];
    const float* Dm     = (const float*)d_in[8];
    const float* W_out  = (const float*)d_in[9];
    const float* b_out  = (const float*)d_in[10];
    float* out = (float*)d_out;

    const int T = 2048, DM = 1024, DS = 256;
    const int M = 8 * T;  // 16384

    char* ws = (char*)d_ws;
    float* u   = (float*)(ws);
    float* u2  = (float*)(ws + (size_t)16 * 1024 * 1024);
    float* h   = (float*)(ws + (size_t)32 * 1024 * 1024);
    float* big = (float*)(ws + (size_t)48 * 1024 * 1024);
    float* g   = (float*)(ws + (size_t)112 * 1024 * 1024);

    dim3 blk(256);
    gemm64<E_BIAS, false><<<dim3(DS / 64, M / 64), blk, 0, stream>>>(
        x, W_in, b_in, nullptr, u, M, DS, DM);
    gemm64<E_NONE, true><<<dim3(DM / 64, M / 64), blk, 0, stream>>>(
        u, Dm, nullptr, nullptr, big, M, DM, DS);
    gemm64<E_NONE, false><<<dim3(DS / 64, M / 64), blk, 0, stream>>>(
        u, Bm, nullptr, nullptr, u2, M, DS, DS);
    gemm64<E_SIG, false><<<dim3(DM / 64, M / 64), blk, 0, stream>>>(
        x, W_gate, b_gate, nullptr, g, M, DM, DM);
    scan_mfma<<<1, 256, 0, stream>>>(Amat, u2, h);
    gemm64<E_ACC, true><<<dim3(DM / 64, M / 64), blk, 0, stream>>>(
        h, Cm, nullptr, nullptr, big, M, DM, DS);
    const int n4 = M * DM / 4;
    ewise<<<n4 / 256, 256, 0, stream>>>(g, big, x, g, n4);
    gemm64<E_BIASRES, false><<<dim3(DM / 64, M / 64), blk, 0, stream>>>(
        g, W_out, b_out, x, out, M, DM, DM);
}